// Round 11
// baseline (291.774 us; speedup 1.0000x reference)
//
#include <hip/hip_runtime.h>
#include <math.h>

// Problem constants (from reference)
#define KN    20000   // vocab
#define KH    40      // LSTM hidden
#define KDW   128     // W_down width
#define KND   16      // noise dim
#define KRW   8       // rw_len
#define KNS   512     // n_sample
#define KCH   79      // ceil(KN / 256) chunks of 256 cols
#define KEPS  1e-20f
#define KLN2  0.69314718055994531f
#define NINF  (-__builtin_inff())

typedef float floatx4 __attribute__((ext_vector_type(4)));

__device__ __forceinline__ float sigmoidf_(float x) { return 1.0f / (1.0f + expf(-x)); }

// pack (score, col) into a monotone-increasing u64 key; larger = better.
// ties on score -> smaller col wins (low field = ~col).
__device__ __forceinline__ unsigned long long packsc_(float v, int col) {
  unsigned u = __float_as_uint(v);
  unsigned key = (u >> 31) ? ~u : (u | 0x80000000u);
  return ((unsigned long long)key << 32) | (unsigned)(~col);
}
// Gumbel(0,1) from uniform u — identical op DAG everywhere it's used.
__device__ __forceinline__ float gumbel_(float u) {
  float t = fmaf(-KLN2, __log2f(u + KEPS), KEPS);   // -ln(u+eps)+eps
  return -KLN2 * __log2f(t);                         // -ln(.)
}

// -------- merged: init MLP+LSTM0 (blocks 0..511) | wnorm partials (blocks 512..590) --------
// wnorm: block b writes wpart[b] = max over its 256 cols of ||W_up[:,j]|| (plain store, no atomics)
__global__ void __launch_bounds__(256) k_init_wnorm(
    const float* __restrict__ z,
    const float* __restrict__ l1w, const float* __restrict__ l1b,
    const float* __restrict__ l2w, const float* __restrict__ l2b,
    const float* __restrict__ l3w, const float* __restrict__ l3b,
    const float* __restrict__ b_ih, const float* __restrict__ b_hh,
    const float* __restrict__ w_hh, const float* __restrict__ W_up,
    float* __restrict__ h, float* __restrict__ c, float* __restrict__ wpart) {
  int tid = threadIdx.x;
  __shared__ float zs[KND], inter[KH], h0[KH], c0[KH], g[4*KH];
  __shared__ float wm[4];
  if (blockIdx.x >= KNS) {
    int b = blockIdx.x - KNS;
    int j = b*256 + tid;
    int lane = tid & 63, grp = tid >> 6;
    float ss = 0.f;
    if (j < KN) {
#pragma unroll
      for (int k = 0; k < KH; ++k) { float w = W_up[k*KN + j]; ss = fmaf(w, w, ss); }
    }
    float wn = sqrtf(ss);          // cols >= KN give 0: harmless for a max of positives
#pragma unroll
    for (int d = 32; d > 0; d >>= 1) wn = fmaxf(wn, __shfl_xor(wn, d, 64));
    if (lane == 0) wm[grp] = wn;
    __syncthreads();
    if (tid == 0) wpart[b] = fmaxf(fmaxf(wm[0], wm[1]), fmaxf(wm[2], wm[3]));
    return;
  }
  // ---- init part ----
  int s = blockIdx.x;
  if (tid < KND) zs[tid] = z[s*KND + tid];
  __syncthreads();
  if (tid < KH) {
    float a = l1b[tid];
#pragma unroll
    for (int k = 0; k < KND; ++k) a = fmaf(zs[k], l1w[k*KH + tid], a);
    inter[tid] = tanhf(a);
  }
  __syncthreads();
  if (tid < KH) {
    float a2 = l2b[tid], a3 = l3b[tid];
#pragma unroll
    for (int k = 0; k < KH; ++k) {
      float iv = inter[k];
      a2 = fmaf(iv, l2w[k*KH + tid], a2);
      a3 = fmaf(iv, l3w[k*KH + tid], a3);
    }
    h0[tid] = tanhf(a2);
    c0[tid] = tanhf(a3);
  }
  __syncthreads();
  if (tid < 4*KH) {
    float a = b_ih[tid] + b_hh[tid];          // x0 = 0 -> no w_ih term
#pragma unroll 8
    for (int k = 0; k < KH; ++k) a = fmaf(h0[k], w_hh[k*4*KH + tid], a);
    g[tid] = a;
  }
  __syncthreads();
  if (tid < KH) {
    float gi = g[tid], gf = g[KH+tid], gg = g[2*KH+tid], go = g[3*KH+tid];
    float cn = sigmoidf_(gf) * c0[tid] + sigmoidf_(gi) * tanhf(gg);
    float hn = sigmoidf_(go) * tanhf(cn);
    h[s*KH + tid] = hn;
    c[s*KH + tid] = cn;
  }
}

// ------- phase A: block = one (s,t) row. Linear 80KB read (gu row) +
//         80KB zero write through L2 (plain stores) + 79 chunk maxima. -------
__global__ void __launch_bounds__(256) k_score_zero(
    const float* __restrict__ gu,           // [RW][NS][KN]
    const float* __restrict__ b_up,         // [KN]
    float* __restrict__ pp,                 // [NS][RW][KCH]
    float* __restrict__ out) {              // [NS][RW][KN]
  int s = blockIdx.x, t = blockIdx.y;
  int tid = threadIdx.x, grp = tid >> 6, lane = tid & 63;
  __shared__ float cm[KCH + 1];
  const float* urow = gu + ((size_t)t*KNS + s)*KN;
  float* orow = out + ((size_t)s*KRW + t)*KN;
  floatx4 zv = (floatx4)(0.f);
#pragma unroll 4
  for (int it = 0; it < 20; ++it) {         // 20*256 float4 >= 5000
    int i = it*256 + tid;                   // float4 index
    int col = i*4;
    bool v = col < KN;
    float m = NINF;
    if (v) {
      floatx4 u4 = *(const floatx4*)(urow + col);
      *(floatx4*)(orow + col) = zv;          // normal store (L2-cached) — A/B vs NT
      floatx4 b4 = *(const floatx4*)(b_up + col);
      float k0 = gumbel_(u4[0]) + b4[0];
      float k1 = gumbel_(u4[1]) + b4[1];
      float k2 = gumbel_(u4[2]) + b4[2];
      float k3 = gumbel_(u4[3]) + b4[3];
      m = fmaxf(fmaxf(k0, k1), fmaxf(k2, k3));
    }
#pragma unroll
    for (int d = 32; d > 0; d >>= 1) m = fmaxf(m, __shfl_xor(m, d, 64));
    int ch = it*4 + grp;                    // 256 cols per (it,grp)
    if (lane == 0 && ch < KCH) cm[ch] = m;
  }
  __syncthreads();
  if (tid < KCH) pp[((size_t)s*KRW + t)*KCH + tid] = cm[tid];
}

// ------- phase B: block = sample, loops t=0..7. pp preloaded to LDS; wave0
//         reduces wpart -> wnm, builds candidate list via ballot; bound-pruned
//         exact rescan -> spike write -> LSTM advance. -------
__global__ void __launch_bounds__(256) k_resolve(
    const float* __restrict__ pp,           // [NS][RW][KCH]
    const float* __restrict__ gu,
    const float* __restrict__ W_up, const float* __restrict__ b_up,
    const float* __restrict__ wpart,        // [KCH]
    const float* __restrict__ hg, const float* __restrict__ cg,
    const float* __restrict__ W_down,
    const float* __restrict__ w_ih, const float* __restrict__ w_hh,
    const float* __restrict__ b_ih, const float* __restrict__ b_hh,
    float* __restrict__ out) {
  int s = blockIdx.x, tid = threadIdx.x;
  int wave = tid >> 6, lane = tid & 63;
  __shared__ float ppl[KRW*KCH];            // 632 floats
  __shared__ float hs[KH], cs[KH], xs[KDW], g[4*KH];
  __shared__ float sThr;
  __shared__ int cand[KCH], ncandS, widxS;
  __shared__ unsigned long long wbest[4];

  for (int j = tid; j < KRW*KCH; j += 256) ppl[j] = pp[(size_t)s*KRW*KCH + j];
  if (tid < KH) { hs[tid] = hg[s*KH + tid]; cs[tid] = cg[s*KH + tid]; }
  __syncthreads();

  float wnm = 0.f, hn = 0.f;                // wave0-resident
  if (wave == 0) {
    float a = (lane < KCH) ? wpart[lane] : NINF;
    float b = (lane + 64 < KCH) ? wpart[lane + 64] : NINF;
    float m = fmaxf(a, b);
#pragma unroll
    for (int d = 32; d > 0; d >>= 1) m = fmaxf(m, __shfl_xor(m, d, 64));
    wnm = m;
    float x = (lane < KH) ? hs[lane] : 0.f;
    float vv = x * x;
#pragma unroll
    for (int d = 32; d > 0; d >>= 1) vv += __shfl_xor(vv, d, 64);
    hn = sqrtf(vv);
  }

  for (int t = 0; t < KRW; ++t) {
    // --- wave0: global max, threshold, candidate list (ballot compaction) ---
    if (wave == 0) {
      const float* pt = ppl + t*KCH;
      float a = pt[lane];                              // lane 0..63 < 79
      float b = (lane + 64 < KCH) ? pt[lane + 64] : NINF;
      float m = fmaxf(a, b);
#pragma unroll
      for (int d = 32; d > 0; d >>= 1) m = fmaxf(m, __shfl_xor(m, d, 64));
      float thr = m - 2.0f * (hn * wnm * 1.001f + 1e-4f);   // safe |h.w_j| bound
      bool c0 = a >= thr;
      bool c1 = (lane + 64 < KCH) && (b >= thr);
      unsigned long long m0 = __ballot(c0), m1 = __ballot(c1);
      unsigned long long lm = ((1ull << lane) - 1ull);      // bits below lane
      if (c0) cand[__popcll(m0 & lm)] = lane;
      if (c1) cand[__popcll(m0) + __popcll(m1 & lm)] = lane + 64;
      if (lane == 0) { ncandS = (int)(__popcll(m0) + __popcll(m1)); sThr = thr; }
    }
    __syncthreads();                                   // sync 1: cand/thr published
    int nc = ncandS;
    float thr = sThr;
    unsigned long long best = 0ull;
    const float* urow = gu + ((size_t)t*KNS + s)*KN;
    for (int ci = 0; ci < nc; ++ci) {                  // usually 1-2
      int col = cand[ci]*256 + tid;
      if (col < KN) {
        float key = gumbel_(urow[col]) + b_up[col];    // identical DAG to k_score_zero
        if (key >= thr) {
          float sc = key;                              // exact score
#pragma unroll
          for (int k = 0; k < KH; ++k) sc = fmaf(hs[k], W_up[k*KN + col], sc);
          unsigned long long pk = packsc_(sc, col);
          if (pk > best) best = pk;
        }
      }
    }
#pragma unroll
    for (int d = 32; d > 0; d >>= 1) {
      unsigned long long q = (unsigned long long)__shfl_xor((long long)best, d, 64);
      if (q > best) best = q;
    }
    if (lane == 0) wbest[wave] = best;
    __syncthreads();                                   // sync 2: per-wave bests ready
    if (tid == 0) {
      unsigned long long fb = wbest[0];
      if (wbest[1] > fb) fb = wbest[1];
      if (wbest[2] > fb) fb = wbest[2];
      if (wbest[3] > fb) fb = wbest[3];
      int w = (int)(~(unsigned)(fb & 0xFFFFFFFFull));
      widxS = w;
      out[((size_t)s*KRW + t)*KN + w] = 1.0f;          // spike (zeros laid by score)
    }
    __syncthreads();                                   // sync 3: widx published
    // --- LSTM advance for next step ---
    if (t < KRW - 1) {
      if (tid < KDW) xs[tid] = W_down[(size_t)widxS*KDW + tid];
      __syncthreads();                                 // sync 4: xs ready
      if (tid < 4*KH) {
        float a = b_ih[tid] + b_hh[tid];
#pragma unroll 8
        for (int k = 0; k < KDW; ++k) a = fmaf(xs[k], w_ih[k*4*KH + tid], a);
#pragma unroll 8
        for (int k = 0; k < KH; ++k) a = fmaf(hs[k], w_hh[k*4*KH + tid], a);
        g[tid] = a;
      }
      __syncthreads();                                 // sync 5: gates ready
      if (tid < KH) {
        float gi = g[tid], gf = g[KH+tid], gg2 = g[2*KH+tid], go = g[3*KH+tid];
        float cn = sigmoidf_(gf) * cs[tid] + sigmoidf_(gi) * tanhf(gg2);
        float hn_ = sigmoidf_(go) * tanhf(cn);
        hs[tid] = hn_; cs[tid] = cn;
      }
      // wave0 refreshes ||h|| from its own lanes' writes (within-wave ordering);
      // next loop's sync 1 publishes hs to the other waves before their rescan.
      if (wave == 0) {
        float x = (lane < KH) ? hs[lane] : 0.f;
        float vv = x * x;
#pragma unroll
        for (int d = 32; d > 0; d >>= 1) vv += __shfl_xor(vv, d, 64);
        hn = sqrtf(vv);
      }
    }
  }
}

extern "C" void kernel_launch(void* const* d_in, const int* in_sizes, int n_in,
                              void* d_out, int out_size, void* d_ws, size_t ws_size,
                              hipStream_t stream) {
  const float* z      = (const float*)d_in[0];
  const float* gu     = (const float*)d_in[1];
  const float* l1w    = (const float*)d_in[2];
  const float* l1b    = (const float*)d_in[3];
  const float* l2w    = (const float*)d_in[4];
  const float* l2b    = (const float*)d_in[5];
  const float* l3w    = (const float*)d_in[6];
  const float* l3b    = (const float*)d_in[7];
  const float* w_ih   = (const float*)d_in[8];
  const float* w_hh   = (const float*)d_in[9];
  const float* b_ih   = (const float*)d_in[10];
  const float* b_hh   = (const float*)d_in[11];
  const float* W_up   = (const float*)d_in[12];
  const float* b_up   = (const float*)d_in[13];
  const float* W_down = (const float*)d_in[14];
  float* out = (float*)d_out;

  // workspace layout (~1.46 MB), every byte rewritten each call
  char* ws = (char*)d_ws;
  float* h  = (float*)(ws);                                    // 512*40 f32
  float* c  = (float*)(ws + (size_t)KNS*KH*4);                 // 512*40 f32
  float* pp = (float*)(ws + (size_t)2*KNS*KH*4);               // 512*8*79 f32
  float* wpart = (float*)(ws + (size_t)2*KNS*KH*4 + (size_t)KNS*KRW*KCH*4); // 79 f32

  k_init_wnorm<<<KNS + KCH, 256, 0, stream>>>(z, l1w, l1b, l2w, l2b, l3w, l3b,
                                              b_ih, b_hh, w_hh, W_up, h, c, wpart);

  k_score_zero<<<dim3(KNS, KRW), 256, 0, stream>>>(gu, b_up, pp, out);

  k_resolve<<<KNS, 256, 0, stream>>>(pp, gu, W_up, b_up, wpart, h, c,
                                     W_down, w_ih, w_hh, b_ih, b_hh, out);
}

// Round 12
// 263.218 us; speedup vs baseline: 1.1085x; 1.1085x over previous
//
#include <hip/hip_runtime.h>
#include <math.h>

// Problem constants (from reference)
#define KN    20000   // vocab
#define KH    40      // LSTM hidden
#define KDW   128     // W_down width
#define KND   16      // noise dim
#define KRW   8       // rw_len
#define KNS   512     // n_sample
#define KCH   79      // ceil(KN / 256) chunks of 256 cols
#define KEPS  1e-20f
#define KLN2  0.69314718055994531f
#define NINF  (-__builtin_inff())

typedef float floatx4 __attribute__((ext_vector_type(4)));

__device__ __forceinline__ float sigmoidf_(float x) { return 1.0f / (1.0f + expf(-x)); }

// pack (score, col) into a monotone-increasing u64 key; larger = better.
// ties on score -> smaller col wins (low field = ~col).
__device__ __forceinline__ unsigned long long packsc_(float v, int col) {
  unsigned u = __float_as_uint(v);
  unsigned key = (u >> 31) ? ~u : (u | 0x80000000u);
  return ((unsigned long long)key << 32) | (unsigned)(~col);
}
// Gumbel(0,1) from uniform u — identical op DAG everywhere it's used.
__device__ __forceinline__ float gumbel_(float u) {
  float t = fmaf(-KLN2, __log2f(u + KEPS), KEPS);   // -ln(u+eps)+eps
  return -KLN2 * __log2f(t);                         // -ln(.)
}

// -------- merged: init MLP+LSTM0 (blocks 0..511) | wnorm partials (blocks 512..590) --------
__global__ void __launch_bounds__(256) k_init_wnorm(
    const float* __restrict__ z,
    const float* __restrict__ l1w, const float* __restrict__ l1b,
    const float* __restrict__ l2w, const float* __restrict__ l2b,
    const float* __restrict__ l3w, const float* __restrict__ l3b,
    const float* __restrict__ b_ih, const float* __restrict__ b_hh,
    const float* __restrict__ w_hh, const float* __restrict__ W_up,
    float* __restrict__ h, float* __restrict__ c, float* __restrict__ wpart) {
  int tid = threadIdx.x;
  __shared__ float zs[KND], inter[KH], h0[KH], c0[KH], g[4*KH];
  __shared__ float wm[4];
  if (blockIdx.x >= KNS) {
    int b = blockIdx.x - KNS;
    int j = b*256 + tid;
    int lane = tid & 63, grp = tid >> 6;
    float ss = 0.f;
    if (j < KN) {
#pragma unroll
      for (int k = 0; k < KH; ++k) { float w = W_up[k*KN + j]; ss = fmaf(w, w, ss); }
    }
    float wn = sqrtf(ss);          // cols >= KN give 0: harmless for a max of positives
#pragma unroll
    for (int d = 32; d > 0; d >>= 1) wn = fmaxf(wn, __shfl_xor(wn, d, 64));
    if (lane == 0) wm[grp] = wn;
    __syncthreads();
    if (tid == 0) wpart[b] = fmaxf(fmaxf(wm[0], wm[1]), fmaxf(wm[2], wm[3]));
    return;
  }
  // ---- init part ----
  int s = blockIdx.x;
  if (tid < KND) zs[tid] = z[s*KND + tid];
  __syncthreads();
  if (tid < KH) {
    float a = l1b[tid];
#pragma unroll
    for (int k = 0; k < KND; ++k) a = fmaf(zs[k], l1w[k*KH + tid], a);
    inter[tid] = tanhf(a);
  }
  __syncthreads();
  if (tid < KH) {
    float a2 = l2b[tid], a3 = l3b[tid];
#pragma unroll
    for (int k = 0; k < KH; ++k) {
      float iv = inter[k];
      a2 = fmaf(iv, l2w[k*KH + tid], a2);
      a3 = fmaf(iv, l3w[k*KH + tid], a3);
    }
    h0[tid] = tanhf(a2);
    c0[tid] = tanhf(a3);
  }
  __syncthreads();
  if (tid < 4*KH) {
    float a = b_ih[tid] + b_hh[tid];          // x0 = 0 -> no w_ih term
#pragma unroll 8
    for (int k = 0; k < KH; ++k) a = fmaf(h0[k], w_hh[k*4*KH + tid], a);
    g[tid] = a;
  }
  __syncthreads();
  if (tid < KH) {
    float gi = g[tid], gf = g[KH+tid], gg = g[2*KH+tid], go = g[3*KH+tid];
    float cn = sigmoidf_(gf) * c0[tid] + sigmoidf_(gi) * tanhf(gg);
    float hn = sigmoidf_(go) * tanhf(cn);
    h[s*KH + tid] = hn;
    c[s*KH + tid] = cn;
  }
}

// ------- phase A: block = one (s,t) row. Three strict phases per wave:
//         (1) ALL 20 u4 loads upfront + compute m[20], (2) batched shuffle
//         reduce -> pp, (3) ALL 20 NT zero stores LAST (no load after store). -------
__global__ void __launch_bounds__(256) k_score_zero(
    const float* __restrict__ gu,           // [RW][NS][KN]
    const float* __restrict__ b_up,         // [KN]
    float* __restrict__ pp,                 // [NS][RW][KCH]
    float* __restrict__ out) {              // [NS][RW][KN]
  int s = blockIdx.x, t = blockIdx.y;
  int tid = threadIdx.x, grp = tid >> 6, lane = tid & 63;
  __shared__ float cm[KCH + 1];
  const float* urow = gu + ((size_t)t*KNS + s)*KN;
  float* orow = out + ((size_t)s*KRW + t)*KN;

  // ---- phase 1a: issue ALL 20 u4 loads (20KB MLP per wave, one drain) ----
  floatx4 u4[20];
#pragma unroll
  for (int it = 0; it < 20; ++it) {
    int col = (it*256 + tid) * 4;
    u4[it] = *(const floatx4*)(urow + (col < KN ? col : KN - 4));
  }
  // ---- phase 1b: compute per-(it) maxima into registers (b4 = L2 hits) ----
  float m[20];
#pragma unroll
  for (int it = 0; it < 20; ++it) {
    int col = (it*256 + tid) * 4;
    bool v = col < KN;
    floatx4 b4 = *(const floatx4*)(b_up + (v ? col : 0));
    float k0 = gumbel_(u4[it][0]) + b4[0];
    float k1 = gumbel_(u4[it][1]) + b4[1];
    float k2 = gumbel_(u4[it][2]) + b4[2];
    float k3 = gumbel_(u4[it][3]) + b4[3];
    m[it] = v ? fmaxf(fmaxf(k0, k1), fmaxf(k2, k3)) : NINF;
  }
  // ---- phase 2: batched shuffle reduce (20 independent chains, pipelined DS) ----
#pragma unroll
  for (int d = 32; d > 0; d >>= 1) {
#pragma unroll
    for (int it = 0; it < 20; ++it)
      m[it] = fmaxf(m[it], __shfl_xor(m[it], d, 64));
  }
#pragma unroll
  for (int it = 0; it < 20; ++it) {
    int ch = it*4 + grp;
    if (lane == 0 && ch < KCH) cm[ch] = m[it];
  }
  __syncthreads();
  if (tid < KCH) pp[((size_t)s*KRW + t)*KCH + tid] = cm[tid];

  // ---- phase 3: NT zero stores LAST — never followed by a load in-wave ----
  floatx4 zv = (floatx4)(0.f);
#pragma unroll
  for (int it = 0; it < 20; ++it) {
    int col = (it*256 + tid) * 4;
    if (col < KN) __builtin_nontemporal_store(zv, (floatx4*)(orow + col));
  }
}

// ------- phase B: block = sample, loops t=0..7. pp preloaded to LDS; wave0
//         reduces wpart -> wnm, builds candidate list via ballot; bound-pruned
//         exact rescan -> spike write -> LSTM advance. (identical to R10) -------
__global__ void __launch_bounds__(256) k_resolve(
    const float* __restrict__ pp,           // [NS][RW][KCH]
    const float* __restrict__ gu,
    const float* __restrict__ W_up, const float* __restrict__ b_up,
    const float* __restrict__ wpart,        // [KCH]
    const float* __restrict__ hg, const float* __restrict__ cg,
    const float* __restrict__ W_down,
    const float* __restrict__ w_ih, const float* __restrict__ w_hh,
    const float* __restrict__ b_ih, const float* __restrict__ b_hh,
    float* __restrict__ out) {
  int s = blockIdx.x, tid = threadIdx.x;
  int wave = tid >> 6, lane = tid & 63;
  __shared__ float ppl[KRW*KCH];            // 632 floats
  __shared__ float hs[KH], cs[KH], xs[KDW], g[4*KH];
  __shared__ float sThr;
  __shared__ int cand[KCH], ncandS, widxS;
  __shared__ unsigned long long wbest[4];

  for (int j = tid; j < KRW*KCH; j += 256) ppl[j] = pp[(size_t)s*KRW*KCH + j];
  if (tid < KH) { hs[tid] = hg[s*KH + tid]; cs[tid] = cg[s*KH + tid]; }
  __syncthreads();

  float wnm = 0.f, hn = 0.f;                // wave0-resident
  if (wave == 0) {
    float a = (lane < KCH) ? wpart[lane] : NINF;
    float b = (lane + 64 < KCH) ? wpart[lane + 64] : NINF;
    float m = fmaxf(a, b);
#pragma unroll
    for (int d = 32; d > 0; d >>= 1) m = fmaxf(m, __shfl_xor(m, d, 64));
    wnm = m;
    float x = (lane < KH) ? hs[lane] : 0.f;
    float vv = x * x;
#pragma unroll
    for (int d = 32; d > 0; d >>= 1) vv += __shfl_xor(vv, d, 64);
    hn = sqrtf(vv);
  }

  for (int t = 0; t < KRW; ++t) {
    // --- wave0: global max, threshold, candidate list (ballot compaction) ---
    if (wave == 0) {
      const float* pt = ppl + t*KCH;
      float a = pt[lane];                              // lane 0..63 < 79
      float b = (lane + 64 < KCH) ? pt[lane + 64] : NINF;
      float m = fmaxf(a, b);
#pragma unroll
      for (int d = 32; d > 0; d >>= 1) m = fmaxf(m, __shfl_xor(m, d, 64));
      float thr = m - 2.0f * (hn * wnm * 1.001f + 1e-4f);   // safe |h.w_j| bound
      bool c0 = a >= thr;
      bool c1 = (lane + 64 < KCH) && (b >= thr);
      unsigned long long m0 = __ballot(c0), m1 = __ballot(c1);
      unsigned long long lm = ((1ull << lane) - 1ull);      // bits below lane
      if (c0) cand[__popcll(m0 & lm)] = lane;
      if (c1) cand[__popcll(m0) + __popcll(m1 & lm)] = lane + 64;
      if (lane == 0) { ncandS = (int)(__popcll(m0) + __popcll(m1)); sThr = thr; }
    }
    __syncthreads();                                   // sync 1: cand/thr published
    int nc = ncandS;
    float thr = sThr;
    unsigned long long best = 0ull;
    const float* urow = gu + ((size_t)t*KNS + s)*KN;
    for (int ci = 0; ci < nc; ++ci) {                  // usually 1-2
      int col = cand[ci]*256 + tid;
      if (col < KN) {
        float key = gumbel_(urow[col]) + b_up[col];    // identical DAG to k_score_zero
        if (key >= thr) {
          float sc = key;                              // exact score
#pragma unroll
          for (int k = 0; k < KH; ++k) sc = fmaf(hs[k], W_up[k*KN + col], sc);
          unsigned long long pk = packsc_(sc, col);
          if (pk > best) best = pk;
        }
      }
    }
#pragma unroll
    for (int d = 32; d > 0; d >>= 1) {
      unsigned long long q = (unsigned long long)__shfl_xor((long long)best, d, 64);
      if (q > best) best = q;
    }
    if (lane == 0) wbest[wave] = best;
    __syncthreads();                                   // sync 2: per-wave bests ready
    if (tid == 0) {
      unsigned long long fb = wbest[0];
      if (wbest[1] > fb) fb = wbest[1];
      if (wbest[2] > fb) fb = wbest[2];
      if (wbest[3] > fb) fb = wbest[3];
      int w = (int)(~(unsigned)(fb & 0xFFFFFFFFull));
      widxS = w;
      out[((size_t)s*KRW + t)*KN + w] = 1.0f;          // spike (zeros laid by score)
    }
    __syncthreads();                                   // sync 3: widx published
    // --- LSTM advance for next step ---
    if (t < KRW - 1) {
      if (tid < KDW) xs[tid] = W_down[(size_t)widxS*KDW + tid];
      __syncthreads();                                 // sync 4: xs ready
      if (tid < 4*KH) {
        float a = b_ih[tid] + b_hh[tid];
#pragma unroll 8
        for (int k = 0; k < KDW; ++k) a = fmaf(xs[k], w_ih[k*4*KH + tid], a);
#pragma unroll 8
        for (int k = 0; k < KH; ++k) a = fmaf(hs[k], w_hh[k*4*KH + tid], a);
        g[tid] = a;
      }
      __syncthreads();                                 // sync 5: gates ready
      if (tid < KH) {
        float gi = g[tid], gf = g[KH+tid], gg2 = g[2*KH+tid], go = g[3*KH+tid];
        float cn = sigmoidf_(gf) * cs[tid] + sigmoidf_(gi) * tanhf(gg2);
        float hn_ = sigmoidf_(go) * tanhf(cn);
        hs[tid] = hn_; cs[tid] = cn;
      }
      // wave0 refreshes ||h|| from its own lanes' writes (within-wave ordering);
      // next loop's sync 1 publishes hs to the other waves before their rescan.
      if (wave == 0) {
        float x = (lane < KH) ? hs[lane] : 0.f;
        float vv = x * x;
#pragma unroll
        for (int d = 32; d > 0; d >>= 1) vv += __shfl_xor(vv, d, 64);
        hn = sqrtf(vv);
      }
    }
  }
}

extern "C" void kernel_launch(void* const* d_in, const int* in_sizes, int n_in,
                              void* d_out, int out_size, void* d_ws, size_t ws_size,
                              hipStream_t stream) {
  const float* z      = (const float*)d_in[0];
  const float* gu     = (const float*)d_in[1];
  const float* l1w    = (const float*)d_in[2];
  const float* l1b    = (const float*)d_in[3];
  const float* l2w    = (const float*)d_in[4];
  const float* l2b    = (const float*)d_in[5];
  const float* l3w    = (const float*)d_in[6];
  const float* l3b    = (const float*)d_in[7];
  const float* w_ih   = (const float*)d_in[8];
  const float* w_hh   = (const float*)d_in[9];
  const float* b_ih   = (const float*)d_in[10];
  const float* b_hh   = (const float*)d_in[11];
  const float* W_up   = (const float*)d_in[12];
  const float* b_up   = (const float*)d_in[13];
  const float* W_down = (const float*)d_in[14];
  float* out = (float*)d_out;

  // workspace layout (~1.46 MB), every byte rewritten each call
  char* ws = (char*)d_ws;
  float* h  = (float*)(ws);                                    // 512*40 f32
  float* c  = (float*)(ws + (size_t)KNS*KH*4);                 // 512*40 f32
  float* pp = (float*)(ws + (size_t)2*KNS*KH*4);               // 512*8*79 f32
  float* wpart = (float*)(ws + (size_t)2*KNS*KH*4 + (size_t)KNS*KRW*KCH*4); // 79 f32

  k_init_wnorm<<<KNS + KCH, 256, 0, stream>>>(z, l1w, l1b, l2w, l2b, l3w, l3b,
                                              b_ih, b_hh, w_hh, W_up, h, c, wpart);

  k_score_zero<<<dim3(KNS, KRW), 256, 0, stream>>>(gu, b_up, pp, out);

  k_resolve<<<KNS, 256, 0, stream>>>(pp, gu, W_up, b_up, wpart, h, c,
                                     W_down, w_ih, w_hh, b_ih, b_hh, out);
}